// Round 8
// baseline (552.889 us; speedup 1.0000x reference)
//
#include <hip/hip_runtime.h>
#include <math.h>

#define N_NODES 20000
#define N_EDGES 256000
#define F_IN 1024
#define C_DIM 1000
#define NEG_SLOPE 0.2f

#define MPAD 20224   // 79 * 256
#define KDIM 1024    // padded K for both layers
#define NW 2048      // fused weight rows: [0,1000)=Wl, [1024,2024)=Wr

typedef __attribute__((ext_vector_type(8))) short          bf16x8;
typedef __attribute__((ext_vector_type(8))) unsigned short u16x8;
typedef __attribute__((ext_vector_type(4))) float          f32x4;
typedef unsigned short us;

__device__ __forceinline__ us f2bf(float f) {
  unsigned u = __float_as_uint(f);
  return (us)((u + 0x7FFFu + ((u >> 16) & 1u)) >> 16);   // RNE
}
__device__ __forceinline__ float bf2f(us u) {
  return __uint_as_float(((unsigned)u) << 16);
}

__device__ __forceinline__ void gld16(void* lds, const void* g) {
  __builtin_amdgcn_global_load_lds(
      (const __attribute__((address_space(1))) unsigned int*)g,
      (__attribute__((address_space(3))) unsigned int*)lds, 16, 0, 0);
}

// ===================== CSR build (by dst) =====================
__global__ void count_k(const int* __restrict__ edst, int* __restrict__ counts) {
  int e = blockIdx.x * blockDim.x + threadIdx.x;
  if (e < N_EDGES) atomicAdd(&counts[edst[e]], 1);
}

// one block; thread t owns counts[t*20 .. t*20+19]
__global__ __launch_bounds__(1024)
void scan_k(const int* __restrict__ counts, int* __restrict__ row_ptr, int* __restrict__ cursor) {
  __shared__ int sm[1024];
  int t = threadIdx.x;
  int base = t * 20;
  int loc[20];
  int run = 0;
#pragma unroll
  for (int i = 0; i < 20; ++i) {
    int idx = base + i;
    int v = (idx < N_NODES) ? counts[idx] : 0;
    run += v;
    loc[i] = run;
  }
  sm[t] = run;
  __syncthreads();
  for (int off = 1; off < 1024; off <<= 1) {
    int v = (t >= off) ? sm[t - off] : 0;
    __syncthreads();
    sm[t] += v;
    __syncthreads();
  }
  int excl = (t > 0) ? sm[t - 1] : 0;
#pragma unroll
  for (int i = 0; i < 20; ++i) {
    int idx = base + i;
    if (idx < N_NODES) {
      int e = excl + ((i > 0) ? loc[i - 1] : 0);
      row_ptr[idx] = e;
      cursor[idx] = e;
    }
  }
  if (t == 0) row_ptr[N_NODES] = sm[1023];
}

__global__ void scatter_k(const int* __restrict__ esrc, const float* __restrict__ eattr,
                          const int* __restrict__ edst, int* __restrict__ cursor,
                          int2* __restrict__ spair) {
  int e = blockIdx.x * blockDim.x + threadIdx.x;
  if (e < N_EDGES) {
    int p = atomicAdd(&cursor[edst[e]], 1);
    spair[p] = make_int2(esrc[e], __float_as_int(eattr[e]));
  }
}

// ===================== fp32 -> padded bf16 (rows -> dstRows, cols -> 1024) =====
__global__ void cvt_pad_k(const float* __restrict__ src, us* __restrict__ dst,
                          int R, int C, int dstRows) {
  long total = (long)dstRows * 256;
  for (long i = (long)blockIdx.x * blockDim.x + threadIdx.x; i < total;
       i += (long)gridDim.x * blockDim.x) {
    int row = (int)(i >> 8);
    int c = ((int)(i & 255)) << 2;
    ushort4 o = make_ushort4(0, 0, 0, 0);
    if (row < R && c < C) {
      float4 v = *(const float4*)(src + (long)row * C + c);
      o.x = f2bf(v.x); o.y = f2bf(v.y); o.z = f2bf(v.z); o.w = f2bf(v.w);
    }
    *(ushort4*)(dst + ((long)row << 10) + c) = o;
  }
}

// ===================== bf16 MFMA GEMM: 256x256 tile, 2-slot dbuf =====================
// C[M,2048] = A[MPAD,1024] @ W2[2048,1024]^T. BK=32, 8 waves (2M x 4N,
// per-wave 128x64 = 8x4 frags, 32 MFMA/tile). Round-3-proven __syncthreads
// double-buffer (2 slots = 64KB LDS -> 2 blocks/CU, m114 wave-overlap intact;
// round-7's 3-slot/96KB = 1 block/CU regressed). Zero-bank-conflict XOR
// swizzle (round-7-proven): inverse-swizzled GLOBAL source + swizzled ds_read.
__global__ __launch_bounds__(512, 2)
void gemm_mfma_k(const us* __restrict__ Abf, const us* __restrict__ Wbf,
                 const float* __restrict__ bl, const float* __restrict__ br,
                 us* __restrict__ Cbf) {
  __shared__ us As[2 * 8192];   // 2 x 16KB  (256 rows x 32 k)
  __shared__ us Bs[2 * 8192];   // 2 x 16KB
  const int tid = threadIdx.x;
  const int lane = tid & 63;
  const int wv = tid >> 6;      // 0..7
  const int wr = wv >> 2;       // 0..1 -> M half (128 rows)
  const int wc = wv & 3;        // 0..3 -> N quarter (64 cols)
  const int g = lane >> 4;      // k-chunk 0..3
  const int rA = lane & 15;

  // XCD swizzle: 632 wgs (79 row-tiles x 8 col-tiles), 632%8==0; each XCD gets
  // 79 consecutive wgs = ~10 row-tiles x all col-tiles -> ~5MB A-slice in L2.
  const int wg = (blockIdx.x & 7) * 79 + (blockIdx.x >> 3);
  const long bm = (long)(wg >> 3) * 256;
  const long bn = (long)(wg & 7) * 256;

  f32x4 acc[8][4];
  const f32x4 z4 = {0.f, 0.f, 0.f, 0.f};
#pragma unroll
  for (int i = 0; i < 8; ++i)
#pragma unroll
    for (int j = 0; j < 4; ++j) acc[i][j] = z4;

  // staging sources, inverse-swizzled: chunk i -> row=i>>2, slot=i&3,
  // logical kchunk c = slot ^ ((row>>1)&3)
  const us* srcA[2];
  const us* srcB[2];
#pragma unroll
  for (int r = 0; r < 2; ++r) {
    int i = tid + r * 512;
    int row = i >> 2;
    int c = (i & 3) ^ ((row >> 1) & 3);
    srcA[r] = Abf + (bm + row) * KDIM + c * 8;
    srcB[r] = Wbf + (bn + row) * KDIM + c * 8;
  }

#define STAGE(TT, SLOT)                                               \
  {                                                                   \
    const int k0 = (TT) * 32;                                         \
    us* Ad = As + (SLOT) * 8192;                                      \
    us* Bd = Bs + (SLOT) * 8192;                                      \
    gld16(Ad + wv * 512, srcA[0] + k0);                               \
    gld16(Ad + 4096 + wv * 512, srcA[1] + k0);                        \
    gld16(Bd + wv * 512, srcB[0] + k0);                               \
    gld16(Bd + 4096 + wv * 512, srcB[1] + k0);                        \
  }

#define COMPUTE(SLOT)                                                 \
  {                                                                   \
    const us* Ar = As + (SLOT) * 8192;                                \
    const us* Br = Bs + (SLOT) * 8192;                                \
    bf16x8 av[8], bv[4];                                              \
    _Pragma("unroll")                                                 \
    for (int ni = 0; ni < 4; ++ni) {                                  \
      int row = wc * 64 + ni * 16 + rA;                               \
      bv[ni] = *(const bf16x8*)&Br[row * 32 + ((g ^ ((row >> 1) & 3)) << 3)]; \
    }                                                                 \
    _Pragma("unroll")                                                 \
    for (int mi = 0; mi < 8; ++mi) {                                  \
      int row = wr * 128 + mi * 16 + rA;                              \
      av[mi] = *(const bf16x8*)&Ar[row * 32 + ((g ^ ((row >> 1) & 3)) << 3)]; \
    }                                                                 \
    __builtin_amdgcn_s_setprio(1);                                    \
    _Pragma("unroll")                                                 \
    for (int mi = 0; mi < 8; ++mi)                                    \
      _Pragma("unroll")                                               \
      for (int ni = 0; ni < 4; ++ni)                                  \
        acc[mi][ni] = __builtin_amdgcn_mfma_f32_16x16x32_bf16(av[mi], bv[ni], acc[mi][ni], 0, 0, 0); \
    __builtin_amdgcn_s_setprio(0);                                    \
  }

  // prologue: tile 0 into slot 0; __syncthreads drains + barriers
  STAGE(0, 0)
  __syncthreads();

  for (int t = 0; t < 32; ++t) {
    if (t + 1 < 32) STAGE(t + 1, (t + 1) & 1)
    COMPUTE(t & 1)
    __syncthreads();   // drains next tile's staging + protects read buffer
  }

  // epilogue
  int coln[4]; float biasv[4]; int cok[4];
#pragma unroll
  for (int ni = 0; ni < 4; ++ni) {
    coln[ni] = (int)bn + wc * 64 + ni * 16 + rA;
    int cm = coln[ni] & 1023;
    cok[ni] = (cm < C_DIM);
    biasv[ni] = cok[ni] ? ((coln[ni] < 1024) ? bl[cm] : br[cm]) : 0.f;
  }
#pragma unroll
  for (int mi = 0; mi < 8; ++mi) {
#pragma unroll
    for (int j = 0; j < 4; ++j) {
      int row = (int)bm + wr * 128 + mi * 16 + g * 4 + j;
      if (row < N_NODES) {
#pragma unroll
        for (int ni = 0; ni < 4; ++ni)
          if (cok[ni])
            Cbf[(long)row * NW + coln[ni]] = f2bf(acc[mi][ni][j] + biasv[ni]);
      }
    }
  }
#undef STAGE
#undef COMPUTE
}

// ===================== fused per-dst attention + aggregation =====================
// ONE dst per wave (round-6 proven). Online softmax; edges unrolled x2.
template <int ACT>
__global__ __launch_bounds__(256)
void edge_agg_k(const us* __restrict__ xlr, const int2* __restrict__ spair,
                const int* __restrict__ row_ptr,
                const float* __restrict__ We, const float* __restrict__ att,
                const float* __restrict__ bias, us* __restrict__ hout,
                float* __restrict__ fout) {
  const int wave = threadIdx.x >> 6;
  const int lane = threadIdx.x & 63;
  const int q0 = lane, q1 = lane + 64;
  const bool ok1 = (q1 < 125);

  const int d = (blockIdx.x << 2) | wave;
  if (d >= N_NODES) return;

  float attv[2][8], wev[2][8];
#pragma unroll
  for (int j = 0; j < 2; ++j) {
    int qq = lane + 64 * j;
    if (qq < 125) {
      float4 a0 = ((const float4*)att)[2 * qq], a1 = ((const float4*)att)[2 * qq + 1];
      float4 w0 = ((const float4*)We)[2 * qq],  w1 = ((const float4*)We)[2 * qq + 1];
      attv[j][0] = a0.x; attv[j][1] = a0.y; attv[j][2] = a0.z; attv[j][3] = a0.w;
      attv[j][4] = a1.x; attv[j][5] = a1.y; attv[j][6] = a1.z; attv[j][7] = a1.w;
      wev[j][0] = w0.x; wev[j][1] = w0.y; wev[j][2] = w0.z; wev[j][3] = w0.w;
      wev[j][4] = w1.x; wev[j][5] = w1.y; wev[j][6] = w1.z; wev[j][7] = w1.w;
    } else {
#pragma unroll
      for (int t = 0; t < 8; ++t) { attv[j][t] = 0.f; wev[j][t] = 0.f; }
    }
  }

  const int beg = row_ptr[d];
  const int end = row_ptr[d + 1];

  float xrv[2][8];
  {
    const u16x8* xrp = (const u16x8*)(xlr + (long)d * NW + 1024);
#pragma unroll
    for (int j = 0; j < 2; ++j) {
      int qq = lane + 64 * j;
      if (qq < 125) {
        u16x8 h = xrp[qq];
#pragma unroll
        for (int t = 0; t < 8; ++t) xrv[j][t] = bf2f(h[t]);
      } else {
#pragma unroll
        for (int t = 0; t < 8; ++t) xrv[j][t] = 0.f;
      }
    }
  }

  float m = -INFINITY, denom = 0.f;
  float acc[2][8];
#pragma unroll
  for (int j = 0; j < 2; ++j)
#pragma unroll
    for (int t = 0; t < 8; ++t) acc[j][t] = 0.f;

#define EDGE_LOGIT(PAIR, VH0, VH1, PART)                                   \
  {                                                                        \
    const u16x8* xs = (const u16x8*)(xlr + (long)(PAIR).x * NW);           \
    float ea = __int_as_float((PAIR).y);                                   \
    VH0 = xs[q0];                                                          \
    if (ok1) VH1 = xs[q1];                                                 \
    else { u16x8 zz = {0,0,0,0,0,0,0,0}; VH1 = zz; }                       \
    PART = 0.f;                                                            \
    _Pragma("unroll")                                                      \
    for (int t = 0; t < 8; ++t) {                                          \
      float tt = bf2f(VH0[t]) + xrv[0][t] + ea * wev[0][t];                \
      tt = (tt >= 0.f) ? tt : NEG_SLOPE * tt;                              \
      PART = fmaf(attv[0][t], tt, PART);                                   \
      float uu = bf2f(VH1[t]) + xrv[1][t] + ea * wev[1][t];                \
      uu = (uu >= 0.f) ? uu : NEG_SLOPE * uu;                              \
      PART = fmaf(attv[1][t], uu, PART);                                   \
    }                                                                      \
  }

#define ONLINE_UPDATE(PART, VH0, VH1)                                      \
  {                                                                        \
    if ((PART) > m) {                                                      \
      float sc = __expf(m - (PART));                                       \
      denom = denom * sc + 1.f;                                            \
      _Pragma("unroll")                                                    \
      for (int t = 0; t < 8; ++t) {                                        \
        acc[0][t] = fmaf(acc[0][t], sc, bf2f(VH0[t]));                     \
        acc[1][t] = fmaf(acc[1][t], sc, bf2f(VH1[t]));                     \
      }                                                                    \
      m = (PART);                                                          \
    } else {                                                               \
      float w = __expf((PART) - m);                                        \
      denom += w;                                                          \
      _Pragma("unroll")                                                    \
      for (int t = 0; t < 8; ++t) {                                        \
        acc[0][t] = fmaf(w, bf2f(VH0[t]), acc[0][t]);                      \
        acc[1][t] = fmaf(w, bf2f(VH1[t]), acc[1][t]);                      \
      }                                                                    \
    }                                                                      \
  }

  int i = beg;
  for (; i + 2 <= end; i += 2) {
    int2 p0 = spair[i], p1 = spair[i + 1];
    u16x8 a0, a1, b0, b1;
    float pt0, pt1;
    EDGE_LOGIT(p0, a0, a1, pt0);
    EDGE_LOGIT(p1, b0, b1, pt1);
#pragma unroll
    for (int off = 32; off > 0; off >>= 1) {
      pt0 += __shfl_xor(pt0, off, 64);
      pt1 += __shfl_xor(pt1, off, 64);
    }
    ONLINE_UPDATE(pt0, a0, a1);
    ONLINE_UPDATE(pt1, b0, b1);
  }
  if (i < end) {
    int2 p0 = spair[i];
    u16x8 a0, a1;
    float pt0;
    EDGE_LOGIT(p0, a0, a1, pt0);
#pragma unroll
    for (int off = 32; off > 0; off >>= 1) pt0 += __shfl_xor(pt0, off, 64);
    ONLINE_UPDATE(pt0, a0, a1);
  }
#undef EDGE_LOGIT
#undef ONLINE_UPDATE

  float inv = 1.f / (denom + 1e-16f);
  if (ACT == 0) {
    us* orow = hout + ((long)d << 10);
#pragma unroll
    for (int j = 0; j < 2; ++j) {
      int qq = lane + 64 * j;
      u16x8 pk = {0, 0, 0, 0, 0, 0, 0, 0};
      if (qq < 125) {
        const float4 b0 = ((const float4*)bias)[2 * qq], b1 = ((const float4*)bias)[2 * qq + 1];
        const float bb[8] = {b0.x, b0.y, b0.z, b0.w, b1.x, b1.y, b1.z, b1.w};
#pragma unroll
        for (int t = 0; t < 8; ++t)
          pk[t] = f2bf(fmaxf(fmaf(acc[j][t], inv, bb[t]), 0.f));
      }
      ((u16x8*)orow)[qq] = pk;
    }
  } else {
#pragma unroll
    for (int j = 0; j < 2; ++j) {
      int qq = lane + 64 * j;
      if (qq < 125) {
        const float4 b0 = ((const float4*)bias)[2 * qq], b1 = ((const float4*)bias)[2 * qq + 1];
        const float bb[8] = {b0.x, b0.y, b0.z, b0.w, b1.x, b1.y, b1.z, b1.w};
        float o[8];
#pragma unroll
        for (int t = 0; t < 8; ++t)
          o[t] = 1.f / (1.f + __expf(-fmaf(acc[j][t], inv, bb[t])));
        float4* op = (float4*)(fout + (long)d * C_DIM + 8 * qq);
        op[0] = make_float4(o[0], o[1], o[2], o[3]);
        op[1] = make_float4(o[4], o[5], o[6], o[7]);
      }
    }
  }
}

// ===================== launch =====================
extern "C" void kernel_launch(void* const* d_in, const int* in_sizes, int n_in,
                              void* d_out, int out_size, void* d_ws, size_t ws_size,
                              hipStream_t stream) {
  const float* x     = (const float*)d_in[0];
  const int*   ei    = (const int*)d_in[1];
  const float* eattr = (const float*)d_in[2];
  const float* w1l   = (const float*)d_in[3];
  const float* b1l   = (const float*)d_in[4];
  const float* w1r   = (const float*)d_in[5];
  const float* b1r   = (const float*)d_in[6];
  const float* w1e   = (const float*)d_in[7];
  const float* att1  = (const float*)d_in[8];
  const float* bias1 = (const float*)d_in[9];
  const float* w2l   = (const float*)d_in[10];
  const float* b2l   = (const float*)d_in[11];
  const float* w2r   = (const float*)d_in[12];
  const float* b2r   = (const float*)d_in[13];
  const float* w2e   = (const float*)d_in[14];
  const float* att2  = (const float*)d_in[15];
  const float* bias2 = (const float*)d_in[16];
  float* out = (float*)d_out;

  // ws layout (bytes), total ~134 MB
  char* w = (char*)d_ws;
  us*  xlr  = (us*)w;                                  // 20000*2048*2 = 81,920,000
  us*  Abf  = (us*)(w + 81920000L);                    // 20224*1024*2 = 41,418,752
  us*  W21  = (us*)(w + 123338752L);                   // 2048*1024*2  =  4,194,304
  us*  W22  = (us*)(w + 127533056L);                   // 2048*1024*2  =  4,194,304
  int2* spair = (int2*)(w + 131727360L);               // 256000*8     =  2,048,000
  int* row_ptr = (int*)(w + 133775360L);               // 20001*4
  int* cursor  = row_ptr + (N_NODES + 1);
  int* counts  = cursor + N_NODES;

  const int* esrc = ei;
  const int* edst = ei + N_EDGES;

  // ---- CSR by dst, with sorted (src, eattr) pairs ----
  hipMemsetAsync(counts, 0, N_NODES * sizeof(int), stream);
  count_k<<<(N_EDGES + 255) / 256, 256, 0, stream>>>(edst, counts);
  scan_k<<<1, 1024, 0, stream>>>(counts, row_ptr, cursor);
  scatter_k<<<(N_EDGES + 255) / 256, 256, 0, stream>>>(esrc, eattr, edst, cursor, spair);

  // ---- all weight conversions up-front ----
  cvt_pad_k<<<1024, 256, 0, stream>>>(w1l, W21, C_DIM, F_IN, 1024);
  cvt_pad_k<<<1024, 256, 0, stream>>>(w1r, W21 + 1024 * 1024, C_DIM, F_IN, 1024);
  cvt_pad_k<<<1024, 256, 0, stream>>>(w2l, W22, C_DIM, C_DIM, 1024);
  cvt_pad_k<<<1024, 256, 0, stream>>>(w2r, W22 + 1024 * 1024, C_DIM, C_DIM, 1024);

  // ---- layer 1 ----
  cvt_pad_k<<<4096, 256, 0, stream>>>(x, Abf, N_NODES, F_IN, MPAD);
  gemm_mfma_k<<<632, 512, 0, stream>>>(Abf, W21, b1l, b1r, xlr);
  edge_agg_k<0><<<N_NODES / 4, 256, 0, stream>>>(xlr, spair, row_ptr, w1e, att1, bias1,
                                                 Abf, nullptr);

  // ---- layer 2 (h is bf16 in Abf; pad rows 20000..20223 still zero from cvt) ----
  gemm_mfma_k<<<632, 512, 0, stream>>>(Abf, W22, b2l, b2r, xlr);
  edge_agg_k<1><<<N_NODES / 4, 256, 0, stream>>>(xlr, spair, row_ptr, w2e, att2, bias2,
                                                 nullptr, out);
}

// Round 10
// 524.301 us; speedup vs baseline: 1.0545x; 1.0545x over previous
//
#include <hip/hip_runtime.h>
#include <math.h>

#define N_NODES 20000
#define N_EDGES 256000
#define F_IN 1024
#define C_DIM 1000
#define NEG_SLOPE 0.2f

#define MPAD 20096   // 157 * 128
#define KDIM 1024    // padded K for both layers
#define NW 2048      // fused weight rows: [0,1000)=Wl, [1024,2024)=Wr

typedef __attribute__((ext_vector_type(8))) short          bf16x8;
typedef __attribute__((ext_vector_type(8))) unsigned short u16x8;
typedef __attribute__((ext_vector_type(4))) float          f32x4;
typedef unsigned short us;

__device__ __forceinline__ us f2bf(float f) {
  unsigned u = __float_as_uint(f);
  return (us)((u + 0x7FFFu + ((u >> 16) & 1u)) >> 16);   // RNE
}
__device__ __forceinline__ float bf2f(us u) {
  return __uint_as_float(((unsigned)u) << 16);
}

__device__ __forceinline__ void gld16(void* lds, const void* g) {
  __builtin_amdgcn_global_load_lds(
      (const __attribute__((address_space(1))) unsigned int*)g,
      (__attribute__((address_space(3))) unsigned int*)lds, 16, 0, 0);
}

// ===================== CSR build (by dst) =====================
__global__ void count_k(const int* __restrict__ edst, int* __restrict__ counts) {
  int e = blockIdx.x * blockDim.x + threadIdx.x;
  if (e < N_EDGES) atomicAdd(&counts[edst[e]], 1);
}

// one block; thread t owns counts[t*20 .. t*20+19]
__global__ __launch_bounds__(1024)
void scan_k(const int* __restrict__ counts, int* __restrict__ row_ptr, int* __restrict__ cursor) {
  __shared__ int sm[1024];
  int t = threadIdx.x;
  int base = t * 20;
  int loc[20];
  int run = 0;
#pragma unroll
  for (int i = 0; i < 20; ++i) {
    int idx = base + i;
    int v = (idx < N_NODES) ? counts[idx] : 0;
    run += v;
    loc[i] = run;
  }
  sm[t] = run;
  __syncthreads();
  for (int off = 1; off < 1024; off <<= 1) {
    int v = (t >= off) ? sm[t - off] : 0;
    __syncthreads();
    sm[t] += v;
    __syncthreads();
  }
  int excl = (t > 0) ? sm[t - 1] : 0;
#pragma unroll
  for (int i = 0; i < 20; ++i) {
    int idx = base + i;
    if (idx < N_NODES) {
      int e = excl + ((i > 0) ? loc[i - 1] : 0);
      row_ptr[idx] = e;
      cursor[idx] = e;
    }
  }
  if (t == 0) row_ptr[N_NODES] = sm[1023];
}

__global__ void scatter_k(const int* __restrict__ esrc, const float* __restrict__ eattr,
                          const int* __restrict__ edst, int* __restrict__ cursor,
                          int2* __restrict__ spair) {
  int e = blockIdx.x * blockDim.x + threadIdx.x;
  if (e < N_EDGES) {
    int p = atomicAdd(&cursor[edst[e]], 1);
    spair[p] = make_int2(esrc[e], __float_as_int(eattr[e]));
  }
}

// ===================== fused fp32 -> padded bf16 conversions (one launch) =====
__device__ __forceinline__ void cvt_body(const float* __restrict__ src, us* __restrict__ dst,
                                         int R, int C, int dstRows, int nblk, int bid,
                                         int tid) {
  long total = (long)dstRows * 256;   // one ushort4 (4 cols of the 1024-wide dst) per idx
  for (long i = (long)bid * 256 + tid; i < total; i += (long)nblk * 256) {
    int row = (int)(i >> 8);
    int c = ((int)(i & 255)) << 2;
    ushort4 o = make_ushort4(0, 0, 0, 0);
    if (row < R && c < C) {
      float4 v = *(const float4*)(src + (long)row * C + c);
      o.x = f2bf(v.x); o.y = f2bf(v.y); o.z = f2bf(v.z); o.w = f2bf(v.w);
    }
    *(ushort4*)(dst + ((long)row << 10) + c) = o;
  }
}

// blocks [0,4096): x -> Abf ; [4096,5120): w1l ; [5120,6144): w1r ;
// [6144,7168): w2l ; [7168,8192): w2r
__global__ __launch_bounds__(256)
void cvt_all_k(const float* __restrict__ x,
               const float* __restrict__ w1l, const float* __restrict__ w1r,
               const float* __restrict__ w2l, const float* __restrict__ w2r,
               us* __restrict__ Abf, us* __restrict__ W21, us* __restrict__ W22) {
  int b = blockIdx.x, tid = threadIdx.x;
  if (b < 4096)      cvt_body(x,   Abf,            N_NODES, F_IN,  MPAD, 4096, b,        tid);
  else if (b < 5120) cvt_body(w1l, W21,            C_DIM,   F_IN,  1024, 1024, b - 4096, tid);
  else if (b < 6144) cvt_body(w1r, W21 + 1048576,  C_DIM,   F_IN,  1024, 1024, b - 5120, tid);
  else if (b < 7168) cvt_body(w2l, W22,            C_DIM,   C_DIM, 1024, 1024, b - 6144, tid);
  else               cvt_body(w2r, W22 + 1048576,  C_DIM,   C_DIM, 1024, 1024, b - 7168, tid);
}

// ===================== fused bf16 MFMA GEMM (round-3 structure + XOR swizzle) =====
// C[M,2048] = A[MPAD,1024] @ W2[2048,1024]^T. 128x128 tile, BK=32, 4 waves,
// 2-phase double-buffered staging, XCD-chunked block swizzle. NEW vs round-3:
// 16B-chunk slot = logical ^ (row&3) -> fragment ds_read spreads 16 lanes over
// 4 rows x 4 slots (8-way -> 4-way bank conflict). Inverse-swizzled GLOBAL
// source + swizzled read; gld LDS dest stays linear (rule #21).
__global__ __launch_bounds__(256)
void gemm_mfma_k(const us* __restrict__ Abf, const us* __restrict__ Wbf,
                 const float* __restrict__ bl, const float* __restrict__ br,
                 us* __restrict__ Cbf) {
  __shared__ us As0[4096], As1[4096], Bs0[4096], Bs1[4096];
  const int tid = threadIdx.x;
  const int lane = tid & 63;
  const int wv = tid >> 6;
  const int wr = wv >> 1, wc = wv & 1;

  const int nwg = gridDim.x;
  const int q = nwg >> 3;
  const int wg = (blockIdx.x & 7) * q + (blockIdx.x >> 3);
  const long bm = (long)(wg >> 4) * 128;   // 157 row-tiles
  const long bn = (long)(wg & 15) * 128;   // 16 col-tiles (N=2048)

  f32x4 acc[4][4];
  const f32x4 z4 = {0.f, 0.f, 0.f, 0.f};
#pragma unroll
  for (int i = 0; i < 4; ++i)
#pragma unroll
    for (int j = 0; j < 4; ++j) acc[i][j] = z4;

  // staging sources, inverse-swizzled: chunk i -> row=i>>2, slot=i&3,
  // logical kchunk = slot ^ (row&3)
  const int i0 = tid, i1 = tid + 256;
  const int c0 = (i0 & 3) ^ ((i0 >> 2) & 3);
  const int c1 = (i1 & 3) ^ ((i1 >> 2) & 3);
  const us* gA0 = Abf + (bm + (i0 >> 2)) * KDIM + c0 * 8;
  const us* gA1 = Abf + (bm + (i1 >> 2)) * KDIM + c1 * 8;
  const us* gB0 = Wbf + (bn + (i0 >> 2)) * KDIM + c0 * 8;
  const us* gB1 = Wbf + (bn + (i1 >> 2)) * KDIM + c1 * 8;

  const int g = lane >> 4;
  const int rA = lane & 15;
  const int kbs = (g ^ (rA & 3)) << 3;   // swizzled k-offset (us elements)

  gld16(As0 + wv * 512, gA0);
  gld16(As0 + 2048 + wv * 512, gA1);
  gld16(Bs0 + wv * 512, gB0);
  gld16(Bs0 + 2048 + wv * 512, gB1);
  __syncthreads();

  for (int t = 0; t < 32; ++t) {
    if (t + 1 < 32) {
      int kn = (t + 1) << 5;
      us* dA = ((t + 1) & 1) ? As1 : As0;
      us* dB = ((t + 1) & 1) ? Bs1 : Bs0;
      gld16(dA + wv * 512, gA0 + kn);
      gld16(dA + 2048 + wv * 512, gA1 + kn);
      gld16(dB + wv * 512, gB0 + kn);
      gld16(dB + 2048 + wv * 512, gB1 + kn);
    }
    const us* Ar = (t & 1) ? As1 : As0;
    const us* Br = (t & 1) ? Bs1 : Bs0;
    bf16x8 av[4], bv[4];
#pragma unroll
    for (int mi = 0; mi < 4; ++mi)
      av[mi] = *(const bf16x8*)&Ar[(wr * 64 + mi * 16 + rA) * 32 + kbs];
#pragma unroll
    for (int ni = 0; ni < 4; ++ni)
      bv[ni] = *(const bf16x8*)&Br[(wc * 64 + ni * 16 + rA) * 32 + kbs];
#pragma unroll
    for (int mi = 0; mi < 4; ++mi)
#pragma unroll
      for (int ni = 0; ni < 4; ++ni)
        acc[mi][ni] = __builtin_amdgcn_mfma_f32_16x16x32_bf16(av[mi], bv[ni], acc[mi][ni], 0, 0, 0);
    __syncthreads();
  }

  int coln[4]; float biasv[4]; int cok[4];
#pragma unroll
  for (int ni = 0; ni < 4; ++ni) {
    coln[ni] = (int)bn + wc * 64 + ni * 16 + rA;
    int cm = coln[ni] & 1023;
    cok[ni] = (cm < C_DIM);
    biasv[ni] = cok[ni] ? ((coln[ni] < 1024) ? bl[cm] : br[cm]) : 0.f;
  }
#pragma unroll
  for (int mi = 0; mi < 4; ++mi) {
#pragma unroll
    for (int j = 0; j < 4; ++j) {
      int row = (int)bm + wr * 64 + mi * 16 + g * 4 + j;
      if (row < N_NODES) {
#pragma unroll
        for (int ni = 0; ni < 4; ++ni)
          if (cok[ni])
            Cbf[(long)row * NW + coln[ni]] = f2bf(acc[mi][ni][j] + biasv[ni]);
      }
    }
  }
}

// ===================== fused per-dst attention + aggregation =====================
// ONE dst per wave (round-6 proven). Online softmax; edges unrolled x2.
// Output stores are nontemporal (via ext-vector types; HIP float4 class is
// rejected by the builtin): 78MB streaming writes shouldn't evict the gather
// working set from L2.
template <int ACT>
__global__ __launch_bounds__(256)
void edge_agg_k(const us* __restrict__ xlr, const int2* __restrict__ spair,
                const int* __restrict__ row_ptr,
                const float* __restrict__ We, const float* __restrict__ att,
                const float* __restrict__ bias, us* __restrict__ hout,
                float* __restrict__ fout) {
  const int wave = threadIdx.x >> 6;
  const int lane = threadIdx.x & 63;
  const int q0 = lane, q1 = lane + 64;
  const bool ok1 = (q1 < 125);

  const int d = (blockIdx.x << 2) | wave;
  if (d >= N_NODES) return;

  float attv[2][8], wev[2][8];
#pragma unroll
  for (int j = 0; j < 2; ++j) {
    int qq = lane + 64 * j;
    if (qq < 125) {
      float4 a0 = ((const float4*)att)[2 * qq], a1 = ((const float4*)att)[2 * qq + 1];
      float4 w0 = ((const float4*)We)[2 * qq],  w1 = ((const float4*)We)[2 * qq + 1];
      attv[j][0] = a0.x; attv[j][1] = a0.y; attv[j][2] = a0.z; attv[j][3] = a0.w;
      attv[j][4] = a1.x; attv[j][5] = a1.y; attv[j][6] = a1.z; attv[j][7] = a1.w;
      wev[j][0] = w0.x; wev[j][1] = w0.y; wev[j][2] = w0.z; wev[j][3] = w0.w;
      wev[j][4] = w1.x; wev[j][5] = w1.y; wev[j][6] = w1.z; wev[j][7] = w1.w;
    } else {
#pragma unroll
      for (int t = 0; t < 8; ++t) { attv[j][t] = 0.f; wev[j][t] = 0.f; }
    }
  }

  const int beg = row_ptr[d];
  const int end = row_ptr[d + 1];

  float xrv[2][8];
  {
    const u16x8* xrp = (const u16x8*)(xlr + (long)d * NW + 1024);
#pragma unroll
    for (int j = 0; j < 2; ++j) {
      int qq = lane + 64 * j;
      if (qq < 125) {
        u16x8 h = xrp[qq];
#pragma unroll
        for (int t = 0; t < 8; ++t) xrv[j][t] = bf2f(h[t]);
      } else {
#pragma unroll
        for (int t = 0; t < 8; ++t) xrv[j][t] = 0.f;
      }
    }
  }

  float m = -INFINITY, denom = 0.f;
  float acc[2][8];
#pragma unroll
  for (int j = 0; j < 2; ++j)
#pragma unroll
    for (int t = 0; t < 8; ++t) acc[j][t] = 0.f;

#define EDGE_LOGIT(PAIR, VH0, VH1, PART)                                   \
  {                                                                        \
    const u16x8* xs = (const u16x8*)(xlr + (long)(PAIR).x * NW);           \
    float ea = __int_as_float((PAIR).y);                                   \
    VH0 = xs[q0];                                                          \
    if (ok1) VH1 = xs[q1];                                                 \
    else { u16x8 zz = {0,0,0,0,0,0,0,0}; VH1 = zz; }                       \
    PART = 0.f;                                                            \
    _Pragma("unroll")                                                      \
    for (int t = 0; t < 8; ++t) {                                          \
      float tt = bf2f(VH0[t]) + xrv[0][t] + ea * wev[0][t];                \
      tt = (tt >= 0.f) ? tt : NEG_SLOPE * tt;                              \
      PART = fmaf(attv[0][t], tt, PART);                                   \
      float uu = bf2f(VH1[t]) + xrv[1][t] + ea * wev[1][t];                \
      uu = (uu >= 0.f) ? uu : NEG_SLOPE * uu;                              \
      PART = fmaf(attv[1][t], uu, PART);                                   \
    }                                                                      \
  }

#define ONLINE_UPDATE(PART, VH0, VH1)                                      \
  {                                                                        \
    if ((PART) > m) {                                                      \
      float sc = __expf(m - (PART));                                       \
      denom = denom * sc + 1.f;                                            \
      _Pragma("unroll")                                                    \
      for (int t = 0; t < 8; ++t) {                                        \
        acc[0][t] = fmaf(acc[0][t], sc, bf2f(VH0[t]));                     \
        acc[1][t] = fmaf(acc[1][t], sc, bf2f(VH1[t]));                     \
      }                                                                    \
      m = (PART);                                                          \
    } else {                                                               \
      float w = __expf((PART) - m);                                        \
      denom += w;                                                          \
      _Pragma("unroll")                                                    \
      for (int t = 0; t < 8; ++t) {                                        \
        acc[0][t] = fmaf(w, bf2f(VH0[t]), acc[0][t]);                      \
        acc[1][t] = fmaf(w, bf2f(VH1[t]), acc[1][t]);                      \
      }                                                                    \
    }                                                                      \
  }

  int i = beg;
  for (; i + 2 <= end; i += 2) {
    int2 p0 = spair[i], p1 = spair[i + 1];
    u16x8 a0, a1, b0, b1;
    float pt0, pt1;
    EDGE_LOGIT(p0, a0, a1, pt0);
    EDGE_LOGIT(p1, b0, b1, pt1);
#pragma unroll
    for (int off = 32; off > 0; off >>= 1) {
      pt0 += __shfl_xor(pt0, off, 64);
      pt1 += __shfl_xor(pt1, off, 64);
    }
    ONLINE_UPDATE(pt0, a0, a1);
    ONLINE_UPDATE(pt1, b0, b1);
  }
  if (i < end) {
    int2 p0 = spair[i];
    u16x8 a0, a1;
    float pt0;
    EDGE_LOGIT(p0, a0, a1, pt0);
#pragma unroll
    for (int off = 32; off > 0; off >>= 1) pt0 += __shfl_xor(pt0, off, 64);
    ONLINE_UPDATE(pt0, a0, a1);
  }
#undef EDGE_LOGIT
#undef ONLINE_UPDATE

  float inv = 1.f / (denom + 1e-16f);
  if (ACT == 0) {
    us* orow = hout + ((long)d << 10);
#pragma unroll
    for (int j = 0; j < 2; ++j) {
      int qq = lane + 64 * j;
      u16x8 pk = {0, 0, 0, 0, 0, 0, 0, 0};
      if (qq < 125) {
        const float4 b0 = ((const float4*)bias)[2 * qq], b1 = ((const float4*)bias)[2 * qq + 1];
        const float bb[8] = {b0.x, b0.y, b0.z, b0.w, b1.x, b1.y, b1.z, b1.w};
#pragma unroll
        for (int t = 0; t < 8; ++t)
          pk[t] = f2bf(fmaxf(fmaf(acc[j][t], inv, bb[t]), 0.f));
      }
      __builtin_nontemporal_store(pk, &((u16x8*)orow)[qq]);
    }
  } else {
#pragma unroll
    for (int j = 0; j < 2; ++j) {
      int qq = lane + 64 * j;
      if (qq < 125) {
        const float4 b0 = ((const float4*)bias)[2 * qq], b1 = ((const float4*)bias)[2 * qq + 1];
        const float bb[8] = {b0.x, b0.y, b0.z, b0.w, b1.x, b1.y, b1.z, b1.w};
        float o[8];
#pragma unroll
        for (int t = 0; t < 8; ++t)
          o[t] = 1.f / (1.f + __expf(-fmaf(acc[j][t], inv, bb[t])));
        f32x4* op = (f32x4*)(fout + (long)d * C_DIM + 8 * qq);
        f32x4 v0 = {o[0], o[1], o[2], o[3]};
        f32x4 v1 = {o[4], o[5], o[6], o[7]};
        __builtin_nontemporal_store(v0, op);
        __builtin_nontemporal_store(v1, op + 1);
      }
    }
  }
}

// ===================== launch =====================
extern "C" void kernel_launch(void* const* d_in, const int* in_sizes, int n_in,
                              void* d_out, int out_size, void* d_ws, size_t ws_size,
                              hipStream_t stream) {
  const float* x     = (const float*)d_in[0];
  const int*   ei    = (const int*)d_in[1];
  const float* eattr = (const float*)d_in[2];
  const float* w1l   = (const float*)d_in[3];
  const float* b1l   = (const float*)d_in[4];
  const float* w1r   = (const float*)d_in[5];
  const float* b1r   = (const float*)d_in[6];
  const float* w1e   = (const float*)d_in[7];
  const float* att1  = (const float*)d_in[8];
  const float* bias1 = (const float*)d_in[9];
  const float* w2l   = (const float*)d_in[10];
  const float* b2l   = (const float*)d_in[11];
  const float* w2r   = (const float*)d_in[12];
  const float* b2r   = (const float*)d_in[13];
  const float* w2e   = (const float*)d_in[14];
  const float* att2  = (const float*)d_in[15];
  const float* bias2 = (const float*)d_in[16];
  float* out = (float*)d_out;

  // ws layout (bytes), total ~134 MB
  char* w = (char*)d_ws;
  us*  xlr  = (us*)w;                                  // 20096*2048*2 = 82,313,216
  us*  Abf  = (us*)(w + 82313216L);                    // 20096*1024*2 = 41,156,608
  us*  W21  = (us*)(w + 123469824L);                   // 2048*1024*2  =  4,194,304
  us*  W22  = (us*)(w + 127664128L);                   // 2048*1024*2  =  4,194,304
  int2* spair = (int2*)(w + 131858432L);               // 256000*8     =  2,048,000
  int* row_ptr = (int*)(w + 133906432L);               // 20001*4
  int* cursor  = row_ptr + (N_NODES + 1);
  int* counts  = cursor + N_NODES;

  const int* esrc = ei;
  const int* edst = ei + N_EDGES;

  // ---- CSR by dst, with sorted (src, eattr) pairs ----
  (void)hipMemsetAsync(counts, 0, N_NODES * sizeof(int), stream);
  count_k<<<(N_EDGES + 255) / 256, 256, 0, stream>>>(edst, counts);
  scan_k<<<1, 1024, 0, stream>>>(counts, row_ptr, cursor);
  scatter_k<<<(N_EDGES + 255) / 256, 256, 0, stream>>>(esrc, eattr, edst, cursor, spair);

  // ---- all fp32->bf16 conversions in one launch ----
  cvt_all_k<<<8192, 256, 0, stream>>>(x, w1l, w1r, w2l, w2r, Abf, W21, W22);

  // ---- layer 1 ----
  gemm_mfma_k<<<2512, 256, 0, stream>>>(Abf, W21, b1l, b1r, xlr);
  edge_agg_k<0><<<N_NODES / 4, 256, 0, stream>>>(xlr, spair, row_ptr, w1e, att1, bias1,
                                                 Abf, nullptr);

  // ---- layer 2 (h is bf16 in Abf; pad rows 20000..20095 still zero from cvt) ----
  gemm_mfma_k<<<2512, 256, 0, stream>>>(Abf, W22, b2l, b2r, xlr);
  edge_agg_k<1><<<N_NODES / 4, 256, 0, stream>>>(xlr, spair, row_ptr, w2e, att2, bias2,
                                                 nullptr, out);
}

// Round 11
// 522.888 us; speedup vs baseline: 1.0574x; 1.0027x over previous
//
#include <hip/hip_runtime.h>
#include <math.h>

#define N_NODES 20000
#define N_EDGES 256000
#define F_IN 1024
#define C_DIM 1000
#define NEG_SLOPE 0.2f

#define MPAD 20096   // 157 * 128
#define KDIM 1024    // padded K for both layers
#define NW 2048      // fused weight rows: [0,1000)=Wl, [1024,2024)=Wr

typedef __attribute__((ext_vector_type(8))) short          bf16x8;
typedef __attribute__((ext_vector_type(8))) unsigned short u16x8;
typedef __attribute__((ext_vector_type(4))) float          f32x4;
typedef unsigned short us;

__device__ __forceinline__ us f2bf(float f) {
  unsigned u = __float_as_uint(f);
  return (us)((u + 0x7FFFu + ((u >> 16) & 1u)) >> 16);   // RNE
}
__device__ __forceinline__ float bf2f(us u) {
  return __uint_as_float(((unsigned)u) << 16);
}

__device__ __forceinline__ void gld16(void* lds, const void* g) {
  __builtin_amdgcn_global_load_lds(
      (const __attribute__((address_space(1))) unsigned int*)g,
      (__attribute__((address_space(3))) unsigned int*)lds, 16, 0, 0);
}

// ===================== CSR build (by dst) =====================
__global__ void count_k(const int* __restrict__ edst, int* __restrict__ counts) {
  int e = blockIdx.x * blockDim.x + threadIdx.x;
  if (e < N_EDGES) atomicAdd(&counts[edst[e]], 1);
}

// one block; thread t owns counts[t*20 .. t*20+19]
__global__ __launch_bounds__(1024)
void scan_k(const int* __restrict__ counts, int* __restrict__ row_ptr, int* __restrict__ cursor) {
  __shared__ int sm[1024];
  int t = threadIdx.x;
  int base = t * 20;
  int loc[20];
  int run = 0;
#pragma unroll
  for (int i = 0; i < 20; ++i) {
    int idx = base + i;
    int v = (idx < N_NODES) ? counts[idx] : 0;
    run += v;
    loc[i] = run;
  }
  sm[t] = run;
  __syncthreads();
  for (int off = 1; off < 1024; off <<= 1) {
    int v = (t >= off) ? sm[t - off] : 0;
    __syncthreads();
    sm[t] += v;
    __syncthreads();
  }
  int excl = (t > 0) ? sm[t - 1] : 0;
#pragma unroll
  for (int i = 0; i < 20; ++i) {
    int idx = base + i;
    if (idx < N_NODES) {
      int e = excl + ((i > 0) ? loc[i - 1] : 0);
      row_ptr[idx] = e;
      cursor[idx] = e;
    }
  }
  if (t == 0) row_ptr[N_NODES] = sm[1023];
}

__global__ void scatter_k(const int* __restrict__ esrc, const float* __restrict__ eattr,
                          const int* __restrict__ edst, int* __restrict__ cursor,
                          int2* __restrict__ spair) {
  int e = blockIdx.x * blockDim.x + threadIdx.x;
  if (e < N_EDGES) {
    int p = atomicAdd(&cursor[edst[e]], 1);
    spair[p] = make_int2(esrc[e], __float_as_int(eattr[e]));
  }
}

// ===================== fused fp32 -> padded bf16 conversions (one launch) =====
__device__ __forceinline__ void cvt_body(const float* __restrict__ src, us* __restrict__ dst,
                                         int R, int C, int dstRows, int nblk, int bid,
                                         int tid) {
  long total = (long)dstRows * 256;   // one ushort4 (4 cols of the 1024-wide dst) per idx
  for (long i = (long)bid * 256 + tid; i < total; i += (long)nblk * 256) {
    int row = (int)(i >> 8);
    int c = ((int)(i & 255)) << 2;
    ushort4 o = make_ushort4(0, 0, 0, 0);
    if (row < R && c < C) {
      float4 v = *(const float4*)(src + (long)row * C + c);
      o.x = f2bf(v.x); o.y = f2bf(v.y); o.z = f2bf(v.z); o.w = f2bf(v.w);
    }
    *(ushort4*)(dst + ((long)row << 10) + c) = o;
  }
}

// blocks [0,4096): x -> Abf ; [4096,5120): w1l ; [5120,6144): w1r ;
// [6144,7168): w2l ; [7168,8192): w2r
__global__ __launch_bounds__(256)
void cvt_all_k(const float* __restrict__ x,
               const float* __restrict__ w1l, const float* __restrict__ w1r,
               const float* __restrict__ w2l, const float* __restrict__ w2r,
               us* __restrict__ Abf, us* __restrict__ W21, us* __restrict__ W22) {
  int b = blockIdx.x, tid = threadIdx.x;
  if (b < 4096)      cvt_body(x,   Abf,            N_NODES, F_IN,  MPAD, 4096, b,        tid);
  else if (b < 5120) cvt_body(w1l, W21,            C_DIM,   F_IN,  1024, 1024, b - 4096, tid);
  else if (b < 6144) cvt_body(w1r, W21 + 1048576,  C_DIM,   F_IN,  1024, 1024, b - 5120, tid);
  else if (b < 7168) cvt_body(w2l, W22,            C_DIM,   C_DIM, 1024, 1024, b - 6144, tid);
  else               cvt_body(w2r, W22 + 1048576,  C_DIM,   C_DIM, 1024, 1024, b - 7168, tid);
}

// ===================== fused bf16 MFMA GEMM (round-3 structure + r7-proven swizzle) =====
// C[M,2048] = A[MPAD,1024] @ W2[2048,1024]^T. 128x128 tile, BK=32, 4 waves,
// 2-phase double-buffered staging, XCD-chunked block swizzle. Swizzle uses row
// BITS 1-2 (r7/r8-proven 0-conflict variant): slot = logical ^ ((row>>1)&3).
// Fragment read span = 16*(rA&1) + 4*(g^((rA>>1)&3)) walks all 8 16B spans
// over rA=0..7 -> 2-way bank aliasing = free (m136). Round-10's (row&3)
// variant left the conflict counter untouched at 1.03e7 - wrong bits.
// Inverse-swizzled GLOBAL source + swizzled read; gld LDS dest linear (rule #21).
__global__ __launch_bounds__(256)
void gemm_mfma_k(const us* __restrict__ Abf, const us* __restrict__ Wbf,
                 const float* __restrict__ bl, const float* __restrict__ br,
                 us* __restrict__ Cbf) {
  __shared__ us As0[4096], As1[4096], Bs0[4096], Bs1[4096];
  const int tid = threadIdx.x;
  const int lane = tid & 63;
  const int wv = tid >> 6;
  const int wr = wv >> 1, wc = wv & 1;

  const int nwg = gridDim.x;
  const int q = nwg >> 3;
  const int wg = (blockIdx.x & 7) * q + (blockIdx.x >> 3);
  const long bm = (long)(wg >> 4) * 128;   // 157 row-tiles
  const long bn = (long)(wg & 15) * 128;   // 16 col-tiles (N=2048)

  f32x4 acc[4][4];
  const f32x4 z4 = {0.f, 0.f, 0.f, 0.f};
#pragma unroll
  for (int i = 0; i < 4; ++i)
#pragma unroll
    for (int j = 0; j < 4; ++j) acc[i][j] = z4;

  // staging sources, inverse-swizzled: chunk i -> row=i>>2, slot=i&3,
  // logical kchunk = slot ^ ((row>>1)&3) = (i&3) ^ ((i>>3)&3)
  const int i0 = tid, i1 = tid + 256;
  const int c0 = (i0 & 3) ^ ((i0 >> 3) & 3);
  const int c1 = (i1 & 3) ^ ((i1 >> 3) & 3);
  const us* gA0 = Abf + (bm + (i0 >> 2)) * KDIM + c0 * 8;
  const us* gA1 = Abf + (bm + (i1 >> 2)) * KDIM + c1 * 8;
  const us* gB0 = Wbf + (bn + (i0 >> 2)) * KDIM + c0 * 8;
  const us* gB1 = Wbf + (bn + (i1 >> 2)) * KDIM + c1 * 8;

  const int g = lane >> 4;
  const int rA = lane & 15;
  const int kbs = (g ^ ((rA >> 1) & 3)) << 3;   // swizzled k-offset (us elements)

  gld16(As0 + wv * 512, gA0);
  gld16(As0 + 2048 + wv * 512, gA1);
  gld16(Bs0 + wv * 512, gB0);
  gld16(Bs0 + 2048 + wv * 512, gB1);
  __syncthreads();

  for (int t = 0; t < 32; ++t) {
    if (t + 1 < 32) {
      int kn = (t + 1) << 5;
      us* dA = ((t + 1) & 1) ? As1 : As0;
      us* dB = ((t + 1) & 1) ? Bs1 : Bs0;
      gld16(dA + wv * 512, gA0 + kn);
      gld16(dA + 2048 + wv * 512, gA1 + kn);
      gld16(dB + wv * 512, gB0 + kn);
      gld16(dB + 2048 + wv * 512, gB1 + kn);
    }
    const us* Ar = (t & 1) ? As1 : As0;
    const us* Br = (t & 1) ? Bs1 : Bs0;
    bf16x8 av[4], bv[4];
#pragma unroll
    for (int mi = 0; mi < 4; ++mi)
      av[mi] = *(const bf16x8*)&Ar[(wr * 64 + mi * 16 + rA) * 32 + kbs];
#pragma unroll
    for (int ni = 0; ni < 4; ++ni)
      bv[ni] = *(const bf16x8*)&Br[(wc * 64 + ni * 16 + rA) * 32 + kbs];
#pragma unroll
    for (int mi = 0; mi < 4; ++mi)
#pragma unroll
      for (int ni = 0; ni < 4; ++ni)
        acc[mi][ni] = __builtin_amdgcn_mfma_f32_16x16x32_bf16(av[mi], bv[ni], acc[mi][ni], 0, 0, 0);
    __syncthreads();
  }

  int coln[4]; float biasv[4]; int cok[4];
#pragma unroll
  for (int ni = 0; ni < 4; ++ni) {
    coln[ni] = (int)bn + wc * 64 + ni * 16 + rA;
    int cm = coln[ni] & 1023;
    cok[ni] = (cm < C_DIM);
    biasv[ni] = cok[ni] ? ((coln[ni] < 1024) ? bl[cm] : br[cm]) : 0.f;
  }
#pragma unroll
  for (int mi = 0; mi < 4; ++mi) {
#pragma unroll
    for (int j = 0; j < 4; ++j) {
      int row = (int)bm + wr * 64 + mi * 16 + g * 4 + j;
      if (row < N_NODES) {
#pragma unroll
        for (int ni = 0; ni < 4; ++ni)
          if (cok[ni])
            Cbf[(long)row * NW + coln[ni]] = f2bf(acc[mi][ni][j] + biasv[ni]);
      }
    }
  }
}

// ===================== fused per-dst attention + aggregation =====================
// ONE dst per wave (round-6 proven). Online softmax; edges unrolled x2.
// Output stores nontemporal (ext-vector types): streaming writes shouldn't
// evict the gather working set from L2.
template <int ACT>
__global__ __launch_bounds__(256)
void edge_agg_k(const us* __restrict__ xlr, const int2* __restrict__ spair,
                const int* __restrict__ row_ptr,
                const float* __restrict__ We, const float* __restrict__ att,
                const float* __restrict__ bias, us* __restrict__ hout,
                float* __restrict__ fout) {
  const int wave = threadIdx.x >> 6;
  const int lane = threadIdx.x & 63;
  const int q0 = lane, q1 = lane + 64;
  const bool ok1 = (q1 < 125);

  const int d = (blockIdx.x << 2) | wave;
  if (d >= N_NODES) return;

  float attv[2][8], wev[2][8];
#pragma unroll
  for (int j = 0; j < 2; ++j) {
    int qq = lane + 64 * j;
    if (qq < 125) {
      float4 a0 = ((const float4*)att)[2 * qq], a1 = ((const float4*)att)[2 * qq + 1];
      float4 w0 = ((const float4*)We)[2 * qq],  w1 = ((const float4*)We)[2 * qq + 1];
      attv[j][0] = a0.x; attv[j][1] = a0.y; attv[j][2] = a0.z; attv[j][3] = a0.w;
      attv[j][4] = a1.x; attv[j][5] = a1.y; attv[j][6] = a1.z; attv[j][7] = a1.w;
      wev[j][0] = w0.x; wev[j][1] = w0.y; wev[j][2] = w0.z; wev[j][3] = w0.w;
      wev[j][4] = w1.x; wev[j][5] = w1.y; wev[j][6] = w1.z; wev[j][7] = w1.w;
    } else {
#pragma unroll
      for (int t = 0; t < 8; ++t) { attv[j][t] = 0.f; wev[j][t] = 0.f; }
    }
  }

  const int beg = row_ptr[d];
  const int end = row_ptr[d + 1];

  float xrv[2][8];
  {
    const u16x8* xrp = (const u16x8*)(xlr + (long)d * NW + 1024);
#pragma unroll
    for (int j = 0; j < 2; ++j) {
      int qq = lane + 64 * j;
      if (qq < 125) {
        u16x8 h = xrp[qq];
#pragma unroll
        for (int t = 0; t < 8; ++t) xrv[j][t] = bf2f(h[t]);
      } else {
#pragma unroll
        for (int t = 0; t < 8; ++t) xrv[j][t] = 0.f;
      }
    }
  }

  float m = -INFINITY, denom = 0.f;
  float acc[2][8];
#pragma unroll
  for (int j = 0; j < 2; ++j)
#pragma unroll
    for (int t = 0; t < 8; ++t) acc[j][t] = 0.f;

#define EDGE_LOGIT(PAIR, VH0, VH1, PART)                                   \
  {                                                                        \
    const u16x8* xs = (const u16x8*)(xlr + (long)(PAIR).x * NW);           \
    float ea = __int_as_float((PAIR).y);                                   \
    VH0 = xs[q0];                                                          \
    if (ok1) VH1 = xs[q1];                                                 \
    else { u16x8 zz = {0,0,0,0,0,0,0,0}; VH1 = zz; }                       \
    PART = 0.f;                                                            \
    _Pragma("unroll")                                                      \
    for (int t = 0; t < 8; ++t) {                                          \
      float tt = bf2f(VH0[t]) + xrv[0][t] + ea * wev[0][t];                \
      tt = (tt >= 0.f) ? tt : NEG_SLOPE * tt;                              \
      PART = fmaf(attv[0][t], tt, PART);                                   \
      float uu = bf2f(VH1[t]) + xrv[1][t] + ea * wev[1][t];                \
      uu = (uu >= 0.f) ? uu : NEG_SLOPE * uu;                              \
      PART = fmaf(attv[1][t], uu, PART);                                   \
    }                                                                      \
  }

#define ONLINE_UPDATE(PART, VH0, VH1)                                      \
  {                                                                        \
    if ((PART) > m) {                                                      \
      float sc = __expf(m - (PART));                                       \
      denom = denom * sc + 1.f;                                            \
      _Pragma("unroll")                                                    \
      for (int t = 0; t < 8; ++t) {                                        \
        acc[0][t] = fmaf(acc[0][t], sc, bf2f(VH0[t]));                     \
        acc[1][t] = fmaf(acc[1][t], sc, bf2f(VH1[t]));                     \
      }                                                                    \
      m = (PART);                                                          \
    } else {                                                               \
      float w = __expf((PART) - m);                                        \
      denom += w;                                                          \
      _Pragma("unroll")                                                    \
      for (int t = 0; t < 8; ++t) {                                        \
        acc[0][t] = fmaf(w, bf2f(VH0[t]), acc[0][t]);                      \
        acc[1][t] = fmaf(w, bf2f(VH1[t]), acc[1][t]);                      \
      }                                                                    \
    }                                                                      \
  }

  int i = beg;
  for (; i + 2 <= end; i += 2) {
    int2 p0 = spair[i], p1 = spair[i + 1];
    u16x8 a0, a1, b0, b1;
    float pt0, pt1;
    EDGE_LOGIT(p0, a0, a1, pt0);
    EDGE_LOGIT(p1, b0, b1, pt1);
#pragma unroll
    for (int off = 32; off > 0; off >>= 1) {
      pt0 += __shfl_xor(pt0, off, 64);
      pt1 += __shfl_xor(pt1, off, 64);
    }
    ONLINE_UPDATE(pt0, a0, a1);
    ONLINE_UPDATE(pt1, b0, b1);
  }
  if (i < end) {
    int2 p0 = spair[i];
    u16x8 a0, a1;
    float pt0;
    EDGE_LOGIT(p0, a0, a1, pt0);
#pragma unroll
    for (int off = 32; off > 0; off >>= 1) pt0 += __shfl_xor(pt0, off, 64);
    ONLINE_UPDATE(pt0, a0, a1);
  }
#undef EDGE_LOGIT
#undef ONLINE_UPDATE

  float inv = 1.f / (denom + 1e-16f);
  if (ACT == 0) {
    us* orow = hout + ((long)d << 10);
#pragma unroll
    for (int j = 0; j < 2; ++j) {
      int qq = lane + 64 * j;
      u16x8 pk = {0, 0, 0, 0, 0, 0, 0, 0};
      if (qq < 125) {
        const float4 b0 = ((const float4*)bias)[2 * qq], b1 = ((const float4*)bias)[2 * qq + 1];
        const float bb[8] = {b0.x, b0.y, b0.z, b0.w, b1.x, b1.y, b1.z, b1.w};
#pragma unroll
        for (int t = 0; t < 8; ++t)
          pk[t] = f2bf(fmaxf(fmaf(acc[j][t], inv, bb[t]), 0.f));
      }
      __builtin_nontemporal_store(pk, &((u16x8*)orow)[qq]);
    }
  } else {
#pragma unroll
    for (int j = 0; j < 2; ++j) {
      int qq = lane + 64 * j;
      if (qq < 125) {
        const float4 b0 = ((const float4*)bias)[2 * qq], b1 = ((const float4*)bias)[2 * qq + 1];
        const float bb[8] = {b0.x, b0.y, b0.z, b0.w, b1.x, b1.y, b1.z, b1.w};
        float o[8];
#pragma unroll
        for (int t = 0; t < 8; ++t)
          o[t] = 1.f / (1.f + __expf(-fmaf(acc[j][t], inv, bb[t])));
        f32x4* op = (f32x4*)(fout + (long)d * C_DIM + 8 * qq);
        f32x4 v0 = {o[0], o[1], o[2], o[3]};
        f32x4 v1 = {o[4], o[5], o[6], o[7]};
        __builtin_nontemporal_store(v0, op);
        __builtin_nontemporal_store(v1, op + 1);
      }
    }
  }
}

// ===================== launch =====================
extern "C" void kernel_launch(void* const* d_in, const int* in_sizes, int n_in,
                              void* d_out, int out_size, void* d_ws, size_t ws_size,
                              hipStream_t stream) {
  const float* x     = (const float*)d_in[0];
  const int*   ei    = (const int*)d_in[1];
  const float* eattr = (const float*)d_in[2];
  const float* w1l   = (const float*)d_in[3];
  const float* b1l   = (const float*)d_in[4];
  const float* w1r   = (const float*)d_in[5];
  const float* b1r   = (const float*)d_in[6];
  const float* w1e   = (const float*)d_in[7];
  const float* att1  = (const float*)d_in[8];
  const float* bias1 = (const float*)d_in[9];
  const float* w2l   = (const float*)d_in[10];
  const float* b2l   = (const float*)d_in[11];
  const float* w2r   = (const float*)d_in[12];
  const float* b2r   = (const float*)d_in[13];
  const float* w2e   = (const float*)d_in[14];
  const float* att2  = (const float*)d_in[15];
  const float* bias2 = (const float*)d_in[16];
  float* out = (float*)d_out;

  // ws layout (bytes), total ~134 MB
  char* w = (char*)d_ws;
  us*  xlr  = (us*)w;                                  // 20096*2048*2 = 82,313,216
  us*  Abf  = (us*)(w + 82313216L);                    // 20096*1024*2 = 41,156,608
  us*  W21  = (us*)(w + 123469824L);                   // 2048*1024*2  =  4,194,304
  us*  W22  = (us*)(w + 127664128L);                   // 2048*1024*2  =  4,194,304
  int2* spair = (int2*)(w + 131858432L);               // 256000*8     =  2,048,000
  int* row_ptr = (int*)(w + 133906432L);               // 20001*4
  int* cursor  = row_ptr + (N_NODES + 1);
  int* counts  = cursor + N_NODES;

  const int* esrc = ei;
  const int* edst = ei + N_EDGES;

  // ---- CSR by dst, with sorted (src, eattr) pairs ----
  (void)hipMemsetAsync(counts, 0, N_NODES * sizeof(int), stream);
  count_k<<<(N_EDGES + 255) / 256, 256, 0, stream>>>(edst, counts);
  scan_k<<<1, 1024, 0, stream>>>(counts, row_ptr, cursor);
  scatter_k<<<(N_EDGES + 255) / 256, 256, 0, stream>>>(esrc, eattr, edst, cursor, spair);

  // ---- all fp32->bf16 conversions in one launch ----
  cvt_all_k<<<8192, 256, 0, stream>>>(x, w1l, w1r, w2l, w2r, Abf, W21, W22);

  // ---- layer 1 ----
  gemm_mfma_k<<<2512, 256, 0, stream>>>(Abf, W21, b1l, b1r, xlr);
  edge_agg_k<0><<<N_NODES / 4, 256, 0, stream>>>(xlr, spair, row_ptr, w1e, att1, bias1,
                                                 Abf, nullptr);

  // ---- layer 2 (h is bf16 in Abf; pad rows 20000..20095 still zero from cvt) ----
  gemm_mfma_k<<<2512, 256, 0, stream>>>(Abf, W22, b2l, b2r, xlr);
  edge_agg_k<1><<<N_NODES / 4, 256, 0, stream>>>(xlr, spair, row_ptr, w2e, att2, bias2,
                                                 nullptr, out);
}